// Round 1
// baseline (214.666 us; speedup 1.0000x reference)
//
#include <hip/hip_runtime.h>
#include <hip/hip_bf16.h>

typedef __attribute__((ext_vector_type(8))) short bf16x8;
typedef __attribute__((ext_vector_type(4))) float f32x4;

#define B_N 4096
#define DIM 512
#define NBINS 32768

// workspace byte offsets
#define OFF_HIST   0
#define OFF_PARAMS (NBINS * 4)              // 131072
#define OFF_X2     (OFF_PARAMS + 256)
#define OFF_Y2     (OFF_X2 + B_N * 4)
#define OFF_YSY    (OFF_Y2 + B_N * 4)

static __device__ __forceinline__ unsigned short f2bf_rne(float f) {
    unsigned int u = __float_as_uint(f);
    u += 0x7FFFu + ((u >> 16) & 1u);
    return (unsigned short)(u >> 16);
}
static __device__ __forceinline__ float bf2f(unsigned short h) {
    return __uint_as_float(((unsigned int)h) << 16);
}

// ---------------- K1: row stats: x2[i], y2[j], ysy[j] ----------------
__global__ void k_rowstats(const float* __restrict__ X, const float* __restrict__ Y,
                           const float* __restrict__ SY,
                           float* __restrict__ x2, float* __restrict__ y2,
                           float* __restrict__ ysy) {
    int r = blockIdx.x, t = threadIdx.x;  // 128 threads, one float4 each
    float4 a = ((const float4*)(X + (size_t)r * DIM))[t];
    float4 b = ((const float4*)(Y + (size_t)r * DIM))[t];
    float4 c = ((const float4*)(SY + (size_t)r * DIM))[t];
    float s1 = a.x * a.x + a.y * a.y + a.z * a.z + a.w * a.w;
    float s2 = b.x * b.x + b.y * b.y + b.z * b.z + b.w * b.w;
    float s3 = b.x * c.x + b.y * c.y + b.z * c.z + b.w * c.w;
#pragma unroll
    for (int o = 32; o > 0; o >>= 1) {
        s1 += __shfl_down(s1, o);
        s2 += __shfl_down(s2, o);
        s3 += __shfl_down(s3, o);
    }
    __shared__ float p[3][2];
    if ((t & 63) == 0) { int wv = t >> 6; p[0][wv] = s1; p[1][wv] = s2; p[2][wv] = s3; }
    __syncthreads();
    if (t == 0) {
        x2[r] = p[0][0] + p[0][1];
        y2[r] = p[1][0] + p[1][1];
        ysy[r] = p[2][0] + p[2][1];
    }
}

// ---------------- K2: sample pairwise dist^2 histogram (512x512) ----------------
__global__ void k_hist(const float* __restrict__ X, const float* __restrict__ Y,
                       const float* __restrict__ x2, const float* __restrict__ y2,
                       unsigned int* __restrict__ hist) {
    __shared__ float4 xs[16 * 129];
    __shared__ float4 ys[16 * 129];
    int t = threadIdx.x;  // 256
    int i0 = blockIdx.y * 16, j0 = blockIdx.x * 16;
#pragma unroll
    for (int it = 0; it < 8; ++it) {
        int idx = it * 256 + t;
        int rr = idx >> 7, cc = idx & 127;
        xs[rr * 129 + cc] = ((const float4*)(X + (size_t)(i0 + rr) * DIM))[cc];
        ys[rr * 129 + cc] = ((const float4*)(Y + (size_t)(j0 + rr) * DIM))[cc];
    }
    __syncthreads();
    int ti = t >> 4, tj = t & 15;
    float s = 0.f;
    for (int kk = 0; kk < 128; ++kk) {
        float4 a = xs[ti * 129 + kk];
        float4 b = ys[tj * 129 + kk];
        s += a.x * b.x + a.y * b.y + a.z * b.z + a.w * b.w;
    }
    float d = fmaxf(x2[i0 + ti] + y2[j0 + tj] - 2.f * s, 0.f);
    int bin = (int)(d * 8.0f);
    if (bin > NBINS - 1) bin = NBINS - 1;
    atomicAdd(&hist[bin], 1u);
}

// ---------------- K3: median -> bandwidth params ----------------
__global__ void k_median(const unsigned int* __restrict__ hist, float* __restrict__ params) {
    __shared__ unsigned int part[256];
    int t = threadIdx.x;
    unsigned int s = 0;
    for (int i = 0; i < 128; ++i) s += hist[t * 128 + i];
    part[t] = s;
    __syncthreads();
    if (t == 0) {
        const unsigned int k1 = 131072u, k2 = 131073u;  // 1-indexed middle two of 262144
        float v1 = 0.f, v2 = 0.f;
        int got = 0;
        unsigned int c = 0;
        for (int ch = 0; ch < 256 && got < 2; ++ch) {
            unsigned int nc = c + part[ch];
            if (got < 1 && k1 <= nc) {
                unsigned int cc = c;
                for (int b = 0; b < 128; ++b) {
                    cc += hist[ch * 128 + b];
                    if (cc >= k1) { v1 = ((float)(ch * 128 + b) + 0.5f) * 0.125f; break; }
                }
                got = 1;
            }
            if (got >= 1 && k2 <= nc) {
                unsigned int cc = c;
                for (int b = 0; b < 128; ++b) {
                    cc += hist[ch * 128 + b];
                    if (cc >= k2) { v2 = ((float)(ch * 128 + b) + 0.5f) * 0.125f; break; }
                }
                got = 2;
            }
            c = nc;
        }
        float med = 0.5f * (v1 + v2);
        float bw = sqrtf(med * 0.5f);
        bw = fminf(fmaxf(bw, 0.1f), 10.0f);
        float h2 = bw * bw;
        params[0] = 1.0f / (2.0f * h2);   // for exp
        params[1] = 1.0f / h2;
        params[2] = 1.0f / (h2 * h2);
        params[3] = (float)DIM / h2;
    }
}

// ---------------- K4: fused triple-GEMM + epilogue ----------------
#define BM 128
#define BN 64
#define BK 32
#define TPB 256

// swizzled LDS index (elements); row stride 32 bf16 = 64B; 16B slot ^= (row>>1)&3 -> 2-way max
static __device__ __forceinline__ int swz(int r, int k) {
    return r * 32 + ((((k >> 3) ^ ((r >> 1) & 3))) << 3) + (k & 7);
}

static __device__ __forceinline__ void store_hi(unsigned short* tile, int r, int k0,
                                                float4 v0, float4 v1) {
    bf16x8 h;
    h[0] = (short)f2bf_rne(v0.x); h[1] = (short)f2bf_rne(v0.y);
    h[2] = (short)f2bf_rne(v0.z); h[3] = (short)f2bf_rne(v0.w);
    h[4] = (short)f2bf_rne(v1.x); h[5] = (short)f2bf_rne(v1.y);
    h[6] = (short)f2bf_rne(v1.z); h[7] = (short)f2bf_rne(v1.w);
    *(bf16x8*)&tile[swz(r, k0)] = h;
}

static __device__ __forceinline__ void store_hilo(unsigned short* th, unsigned short* tl,
                                                  int r, int k0, float4 v0, float4 v1) {
    float f[8] = {v0.x, v0.y, v0.z, v0.w, v1.x, v1.y, v1.z, v1.w};
    bf16x8 h, l;
#pragma unroll
    for (int j = 0; j < 8; ++j) {
        unsigned short hh = f2bf_rne(f[j]);
        h[j] = (short)hh;
        l[j] = (short)f2bf_rne(f[j] - bf2f(hh));
    }
    *(bf16x8*)&th[swz(r, k0)] = h;
    *(bf16x8*)&tl[swz(r, k0)] = l;
}

__global__ __launch_bounds__(TPB, 2) void k_main(
    const float* __restrict__ X, const float* __restrict__ SX,
    const float* __restrict__ Y, const float* __restrict__ SY,
    const float* __restrict__ x2g, const float* __restrict__ y2g,
    const float* __restrict__ ysyg, const float* __restrict__ params,
    float* __restrict__ out) {
    __shared__ __align__(16) unsigned short tX[BM * BK];
    __shared__ __align__(16) unsigned short tSXH[BM * BK];
    __shared__ __align__(16) unsigned short tSXL[BM * BK];
    __shared__ __align__(16) unsigned short tY[BN * BK];
    __shared__ __align__(16) unsigned short tSYH[BN * BK];
    __shared__ __align__(16) unsigned short tSYL[BN * BK];
    __shared__ float x2s[BM];
    __shared__ float y2s[BN];
    __shared__ float ysys[BN];

    int t = threadIdx.x;
    int bm = blockIdx.y, bn = blockIdx.x;

    if (t < BM) x2s[t] = x2g[bm * BM + t];
    else if (t < BM + BN) y2s[t - BM] = y2g[bn * BN + (t - BM)];
    else ysys[t - BM - BN] = ysyg[bn * BN + (t - BM - BN)];

    int lane = t & 63;
    int w = t >> 6;          // 0..3
    int wm = w >> 1;         // 0..1 -> rows wm*64
    int wn = w & 1;          // 0..1 -> cols wn*32

    f32x4 axy[4][2], ass[4][2], axsy[4][2];
#pragma unroll
    for (int i = 0; i < 4; ++i)
#pragma unroll
        for (int j = 0; j < 2; ++j) {
            axy[i][j] = (f32x4)0.f; ass[i][j] = (f32x4)0.f; axsy[i][j] = (f32x4)0.f;
        }

    for (int kt = 0; kt < DIM / BK; ++kt) {
        int kb = kt * BK;
        // stage A tiles (128x32): 512 slots over 256 threads
#pragma unroll
        for (int h = 0; h < 2; ++h) {
            int s = t + h * TPB;
            int r = s >> 2;
            int k0 = (s & 3) * 8;
            const float* gx = X + (size_t)(bm * BM + r) * DIM + kb + k0;
            float4 v0 = *(const float4*)(gx);
            float4 v1 = *(const float4*)(gx + 4);
            store_hi(tX, r, k0, v0, v1);
            const float* gs = SX + (size_t)(bm * BM + r) * DIM + kb + k0;
            float4 u0 = *(const float4*)(gs);
            float4 u1 = *(const float4*)(gs + 4);
            store_hilo(tSXH, tSXL, r, k0, u0, u1);
        }
        // stage B tiles (64x32): 256 slots
        {
            int r = t >> 2;
            int k0 = (t & 3) * 8;
            const float* gy = Y + (size_t)(bn * BN + r) * DIM + kb + k0;
            float4 v0 = *(const float4*)(gy);
            float4 v1 = *(const float4*)(gy + 4);
            store_hi(tY, r, k0, v0, v1);
            const float* gq = SY + (size_t)(bn * BN + r) * DIM + kb + k0;
            float4 u0 = *(const float4*)(gq);
            float4 u1 = *(const float4*)(gq + 4);
            store_hilo(tSYH, tSYL, r, k0, u0, u1);
        }
        __syncthreads();

        int fr = lane & 15, fk = (lane >> 4) * 8;
        bf16x8 aX[4], aSH[4], aSL[4];
#pragma unroll
        for (int fm = 0; fm < 4; ++fm) {
            int row = wm * 64 + fm * 16 + fr;
            aX[fm]  = *(const bf16x8*)&tX[swz(row, fk)];
            aSH[fm] = *(const bf16x8*)&tSXH[swz(row, fk)];
            aSL[fm] = *(const bf16x8*)&tSXL[swz(row, fk)];
        }
        bf16x8 bYf[2], bSH[2], bSL[2];
#pragma unroll
        for (int fn = 0; fn < 2; ++fn) {
            int row = wn * 32 + fn * 16 + fr;
            bYf[fn] = *(const bf16x8*)&tY[swz(row, fk)];
            bSH[fn] = *(const bf16x8*)&tSYH[swz(row, fk)];
            bSL[fn] = *(const bf16x8*)&tSYL[swz(row, fk)];
        }
#pragma unroll
        for (int fm = 0; fm < 4; ++fm)
#pragma unroll
            for (int fn = 0; fn < 2; ++fn) {
                axy[fm][fn]  = __builtin_amdgcn_mfma_f32_16x16x32_bf16(aX[fm],  bYf[fn], axy[fm][fn], 0, 0, 0);
                ass[fm][fn]  = __builtin_amdgcn_mfma_f32_16x16x32_bf16(aSH[fm], bSH[fn], ass[fm][fn], 0, 0, 0);
                ass[fm][fn]  = __builtin_amdgcn_mfma_f32_16x16x32_bf16(aSH[fm], bSL[fn], ass[fm][fn], 0, 0, 0);
                ass[fm][fn]  = __builtin_amdgcn_mfma_f32_16x16x32_bf16(aSL[fm], bSH[fn], ass[fm][fn], 0, 0, 0);
                axsy[fm][fn] = __builtin_amdgcn_mfma_f32_16x16x32_bf16(aX[fm],  bSH[fn], axsy[fm][fn], 0, 0, 0);
            }
        __syncthreads();
    }

    // epilogue
    float c0 = params[0], c1 = params[1], c2 = params[2], c3 = params[3];
    int fr = lane & 15, fq = lane >> 4;
#pragma unroll
    for (int fm = 0; fm < 4; ++fm) {
#pragma unroll
        for (int fn = 0; fn < 2; ++fn) {
#pragma unroll
            for (int r = 0; r < 4; ++r) {
                int rl = wm * 64 + fm * 16 + fq * 4 + r;
                int cl = wn * 32 + fn * 16 + fr;
                float d = x2s[rl] + y2s[cl] - 2.0f * axy[fm][fn][r];
                d = fmaxf(d, 0.0f);
                float kv = __expf(-d * c0);
                float res = kv * ass[fm][fn][r]
                          + (axsy[fm][fn][r] - ysys[cl]) * (kv * c1)
                          + d * kv * c2 - kv * c3;
                out[(size_t)(bm * BM + rl) * B_N + (bn * BN + cl)] = res;
            }
        }
    }
}

extern "C" void kernel_launch(void* const* d_in, const int* in_sizes, int n_in,
                              void* d_out, int out_size, void* d_ws, size_t ws_size,
                              hipStream_t stream) {
    const float* x  = (const float*)d_in[0];
    const float* sx = (const float*)d_in[1];
    const float* y  = (const float*)d_in[2];
    const float* sy = (const float*)d_in[3];
    float* out = (float*)d_out;
    char* ws = (char*)d_ws;
    unsigned int* hist = (unsigned int*)(ws + OFF_HIST);
    float* params = (float*)(ws + OFF_PARAMS);
    float* x2 = (float*)(ws + OFF_X2);
    float* y2 = (float*)(ws + OFF_Y2);
    float* ysy = (float*)(ws + OFF_YSY);

    hipMemsetAsync(hist, 0, NBINS * 4, stream);
    k_rowstats<<<B_N, 128, 0, stream>>>(x, y, sy, x2, y2, ysy);
    k_hist<<<dim3(32, 32), dim3(256), 0, stream>>>(x, y, x2, y2, hist);
    k_median<<<1, 256, 0, stream>>>(hist, params);
    k_main<<<dim3(B_N / BN, B_N / BM), TPB, 0, stream>>>(x, sx, y, sy, x2, y2, ysy, params, out);
}

// Round 3
// 136.736 us; speedup vs baseline: 1.5699x; 1.5699x over previous
//
#include <hip/hip_runtime.h>
#include <hip/hip_bf16.h>

typedef __attribute__((ext_vector_type(8))) short bf16x8;
typedef __attribute__((ext_vector_type(4))) float f32x4;

#define B_N 4096
#define DIM 512
#define HBINS 8192

// workspace byte offsets
#define OFF_HIST   0                 // 8192*4 = 32768
#define OFF_PARAMS 32768             // 256
#define OFF_X2     33024             // 16384
#define OFF_Y2     49408             // 16384
#define OFF_YSY    65792             // 16384 -> end 82176
#define OFF_TILES  98304             // 4KB aligned
#define MAT_ELEMS  2097152           // 4096*512 bf16 elems per matrix (4 MB)
#define WS_NEED    (OFF_TILES + (size_t)6 * MAT_ELEMS * 2)

static __device__ __forceinline__ unsigned short f2bf_rne(float f) {
    unsigned int u = __float_as_uint(f);
    u += 0x7FFFu + ((u >> 16) & 1u);
    return (unsigned short)(u >> 16);
}
static __device__ __forceinline__ float bf2f(unsigned short h) {
    return __uint_as_float(((unsigned int)h) << 16);
}

// swizzled LDS/tile index (elements); row stride 32 bf16 = 64B; 16B slot ^= (row>>1)&3
static __device__ __forceinline__ int swz(int r, int k) {
    return r * 32 + ((((k >> 3) ^ ((r >> 1) & 3))) << 3) + (k & 7);
}

// ---------------- K1: row stats: x2[i], y2[j], ysy[j] ----------------
__global__ void k_rowstats(const float* __restrict__ X, const float* __restrict__ Y,
                           const float* __restrict__ SY,
                           float* __restrict__ x2, float* __restrict__ y2,
                           float* __restrict__ ysy) {
    int r = blockIdx.x, t = threadIdx.x;  // 128 threads, one float4 each
    float4 a = ((const float4*)(X + (size_t)r * DIM))[t];
    float4 b = ((const float4*)(Y + (size_t)r * DIM))[t];
    float4 c = ((const float4*)(SY + (size_t)r * DIM))[t];
    float s1 = a.x * a.x + a.y * a.y + a.z * a.z + a.w * a.w;
    float s2 = b.x * b.x + b.y * b.y + b.z * b.z + b.w * b.w;
    float s3 = b.x * c.x + b.y * c.y + b.z * c.z + b.w * c.w;
#pragma unroll
    for (int o = 32; o > 0; o >>= 1) {
        s1 += __shfl_down(s1, o);
        s2 += __shfl_down(s2, o);
        s3 += __shfl_down(s3, o);
    }
    __shared__ float p[3][2];
    if ((t & 63) == 0) { int wv = t >> 6; p[0][wv] = s1; p[1][wv] = s2; p[2][wv] = s3; }
    __syncthreads();
    if (t == 0) {
        x2[r] = p[0][0] + p[0][1];
        y2[r] = p[1][0] + p[1][1];
        ysy[r] = p[2][0] + p[2][1];
    }
}

// ---------------- K2: sample dist^2 histogram, LDS-local ----------------
__global__ void k_hist(const float* __restrict__ X, const float* __restrict__ Y,
                       const float* __restrict__ x2, const float* __restrict__ y2,
                       unsigned int* __restrict__ hist) {
    __shared__ float xs[32][68];
    __shared__ float ys[32][68];
    __shared__ unsigned int hloc[HBINS];
    int t = threadIdx.x;  // 256
    for (int i = t; i < HBINS; i += 256) hloc[i] = 0;
    int i0 = blockIdx.y * 32, j0 = blockIdx.x * 32;
    float a00 = 0.f, a01 = 0.f, a10 = 0.f, a11 = 0.f;
    int ti = (t >> 4) * 2, tj = (t & 15) * 2;
    for (int c = 0; c < 8; ++c) {
        __syncthreads();
        int rr = t >> 3, cc = (t & 7) * 8;
        const float* gx = X + (size_t)(i0 + rr) * DIM + c * 64 + cc;
        *(float4*)&xs[rr][cc] = *(const float4*)gx;
        *(float4*)&xs[rr][cc + 4] = *(const float4*)(gx + 4);
        const float* gy = Y + (size_t)(j0 + rr) * DIM + c * 64 + cc;
        *(float4*)&ys[rr][cc] = *(const float4*)gy;
        *(float4*)&ys[rr][cc + 4] = *(const float4*)(gy + 4);
        __syncthreads();
        for (int kk = 0; kk < 64; ++kk) {
            float a0 = xs[ti][kk], a1 = xs[ti + 1][kk];
            float b0 = ys[tj][kk], b1 = ys[tj + 1][kk];
            a00 += a0 * b0; a01 += a0 * b1; a10 += a1 * b0; a11 += a1 * b1;
        }
    }
    float s[2][2] = {{a00, a01}, {a10, a11}};
#pragma unroll
    for (int ii = 0; ii < 2; ++ii)
#pragma unroll
        for (int jj = 0; jj < 2; ++jj) {
            float d = fmaxf(x2[i0 + ti + ii] + y2[j0 + tj + jj] - 2.f * s[ii][jj], 0.f);
            int bin = (int)(d * 4.0f);
            if (bin > HBINS - 1) bin = HBINS - 1;
            atomicAdd(&hloc[bin], 1u);
        }
    __syncthreads();
    for (int i = t; i < HBINS; i += 256) {
        unsigned int v = hloc[i];
        if (v) atomicAdd(&hist[i], v);
    }
}

// ---------------- K3: median -> bandwidth params ----------------
__global__ void k_median(const unsigned int* __restrict__ hist, float* __restrict__ params) {
    __shared__ unsigned int part[256];
    int t = threadIdx.x;
    unsigned int s = 0;
    for (int i = 0; i < 32; ++i) s += hist[t * 32 + i];
    part[t] = s;
    __syncthreads();
    if (t == 0) {
        const unsigned int k1 = 131072u, k2 = 131073u;
        float v1 = 0.f, v2 = 0.f;
        int got = 0;
        unsigned int c = 0;
        for (int ch = 0; ch < 256 && got < 2; ++ch) {
            unsigned int nc = c + part[ch];
            if (got < 1 && k1 <= nc) {
                unsigned int cc = c;
                for (int b = 0; b < 32; ++b) {
                    cc += hist[ch * 32 + b];
                    if (cc >= k1) { v1 = ((float)(ch * 32 + b) + 0.5f) * 0.25f; break; }
                }
                got = 1;
            }
            if (got >= 1 && k2 <= nc) {
                unsigned int cc = c;
                for (int b = 0; b < 32; ++b) {
                    cc += hist[ch * 32 + b];
                    if (cc >= k2) { v2 = ((float)(ch * 32 + b) + 0.5f) * 0.25f; break; }
                }
                got = 2;
            }
            c = nc;
        }
        float med = 0.5f * (v1 + v2);
        float bw = sqrtf(med * 0.5f);
        bw = fminf(fmaxf(bw, 0.1f), 10.0f);
        float h2 = bw * bw;
        params[0] = 1.0f / (2.0f * h2);
        params[1] = 1.0f / h2;
        params[2] = 1.0f / (h2 * h2);
        params[3] = (float)DIM / h2;
    }
}

// ---------------- K4a: precompute A-side bf16 tile images: X, CH, CL ----------------
// comb = SX + c1*X, split hi/lo. Layout: mat*MAT_ELEMS + (tile*16+kt)*4096 + swz(r,k)
__global__ void k_preA(const float* __restrict__ X, const float* __restrict__ SX,
                       const float* __restrict__ params, unsigned short* __restrict__ tiles) {
    float c1 = params[1];
    int tile = blockIdx.x, kt = blockIdx.y, t = threadIdx.x;
    int r = t >> 1, k0 = (t & 1) * 16;
    const float* gx = X + (size_t)(tile * 128 + r) * DIM + kt * 32 + k0;
    const float* gs = SX + (size_t)(tile * 128 + r) * DIM + kt * 32 + k0;
    unsigned short* dX = tiles + (size_t)(tile * 16 + kt) * 4096;
    unsigned short* dH = dX + MAT_ELEMS;
    unsigned short* dL = dX + 2 * MAT_ELEMS;
#pragma unroll
    for (int half = 0; half < 2; ++half) {
        float4 x0 = *(const float4*)(gx + half * 8);
        float4 x1 = *(const float4*)(gx + half * 8 + 4);
        float4 s0 = *(const float4*)(gs + half * 8);
        float4 s1 = *(const float4*)(gs + half * 8 + 4);
        float xv[8] = {x0.x, x0.y, x0.z, x0.w, x1.x, x1.y, x1.z, x1.w};
        float sv[8] = {s0.x, s0.y, s0.z, s0.w, s1.x, s1.y, s1.z, s1.w};
        bf16x8 hx, hh, hl;
#pragma unroll
        for (int j = 0; j < 8; ++j) {
            hx[j] = (short)f2bf_rne(xv[j]);
            float v = sv[j] + c1 * xv[j];
            unsigned short vh = f2bf_rne(v);
            hh[j] = (short)vh;
            hl[j] = (short)f2bf_rne(v - bf2f(vh));
        }
        int ix = swz(r, k0 + half * 8);
        *(bf16x8*)&dX[ix] = hx;
        *(bf16x8*)&dH[ix] = hh;
        *(bf16x8*)&dL[ix] = hl;
    }
}

// ---------------- K4b: precompute B-side bf16 tile images: Y, SYH, SYL ----------------
__global__ void k_preB(const float* __restrict__ Y, const float* __restrict__ SY,
                       unsigned short* __restrict__ tiles) {
    int tile = blockIdx.x, kt = blockIdx.y, t = threadIdx.x;
    int r = t >> 1, k0 = (t & 1) * 16;
    const float* gy = Y + (size_t)(tile * 128 + r) * DIM + kt * 32 + k0;
    const float* gs = SY + (size_t)(tile * 128 + r) * DIM + kt * 32 + k0;
    unsigned short* dY = tiles + 3 * (size_t)MAT_ELEMS + (size_t)(tile * 16 + kt) * 4096;
    unsigned short* dH = dY + MAT_ELEMS;
    unsigned short* dL = dY + 2 * MAT_ELEMS;
#pragma unroll
    for (int half = 0; half < 2; ++half) {
        float4 y0 = *(const float4*)(gy + half * 8);
        float4 y1 = *(const float4*)(gy + half * 8 + 4);
        float4 s0 = *(const float4*)(gs + half * 8);
        float4 s1 = *(const float4*)(gs + half * 8 + 4);
        float yv[8] = {y0.x, y0.y, y0.z, y0.w, y1.x, y1.y, y1.z, y1.w};
        float sv[8] = {s0.x, s0.y, s0.z, s0.w, s1.x, s1.y, s1.z, s1.w};
        bf16x8 hy, hh, hl;
#pragma unroll
        for (int j = 0; j < 8; ++j) {
            hy[j] = (short)f2bf_rne(yv[j]);
            unsigned short vh = f2bf_rne(sv[j]);
            hh[j] = (short)vh;
            hl[j] = (short)f2bf_rne(sv[j] - bf2f(vh));
        }
        int ix = swz(r, k0 + half * 8);
        *(bf16x8*)&dY[ix] = hy;
        *(bf16x8*)&dH[ix] = hh;
        *(bf16x8*)&dL[ix] = hl;
    }
}

// ---------------- K5: main fused GEMM + epilogue (fast path) ----------------
#define GLD(g, l) __builtin_amdgcn_global_load_lds(                                   \
    (const __attribute__((address_space(1))) void*)(g),                               \
    (__attribute__((address_space(3))) void*)(l), 16, 0, 0)

__global__ __launch_bounds__(256, 2) void k_main(
    const unsigned short* __restrict__ tiles,
    const float* __restrict__ x2g, const float* __restrict__ y2g,
    const float* __restrict__ ysyg, const float* __restrict__ params,
    float* __restrict__ out) {
    __shared__ __align__(16) unsigned short sA[3][4096];  // X, CH, CL (128x32 swizzled)
    __shared__ __align__(16) unsigned short sB[3][4096];  // Y, SYH, SYL
    __shared__ float x2s[128], y2s[128], ysys[128];

    int t = threadIdx.x;
    int bm = blockIdx.y, bn = blockIdx.x;
    if (t < 128) x2s[t] = x2g[bm * 128 + t];
    else { y2s[t - 128] = y2g[bn * 128 + (t - 128)]; ysys[t - 128] = ysyg[bn * 128 + (t - 128)]; }

    int lane = t & 63, w = t >> 6;
    int wm = w >> 1, wn = w & 1;       // wave tile 64x64 at (wm*64, wn*64)
    int fr = lane & 15, fko = (lane >> 4) * 8;

    f32x4 axy[4][4], acb[4][4];
#pragma unroll
    for (int i = 0; i < 4; ++i)
#pragma unroll
        for (int j = 0; j < 4; ++j) { axy[i][j] = (f32x4)0.f; acb[i][j] = (f32x4)0.f; }

    const unsigned short* ga = tiles + (size_t)(bm * 16) * 4096 + t * 8;
    const unsigned short* gb = tiles + 3 * (size_t)MAT_ELEMS + (size_t)(bn * 16) * 4096 + t * 8;

    for (int kt = 0; kt < DIM / 32; ++kt) {
#pragma unroll
        for (int m = 0; m < 3; ++m) {
            GLD(ga + (size_t)m * MAT_ELEMS,        &sA[m][t * 8]);
            GLD(ga + (size_t)m * MAT_ELEMS + 2048, &sA[m][2048 + t * 8]);
            GLD(gb + (size_t)m * MAT_ELEMS,        &sB[m][t * 8]);
            GLD(gb + (size_t)m * MAT_ELEMS + 2048, &sB[m][2048 + t * 8]);
        }
        ga += 4096; gb += 4096;
        __syncthreads();

        bf16x8 aX[4], aH[4], aL[4];
#pragma unroll
        for (int fm = 0; fm < 4; ++fm) {
            int ix = swz(wm * 64 + fm * 16 + fr, fko);
            aX[fm] = *(const bf16x8*)&sA[0][ix];
            aH[fm] = *(const bf16x8*)&sA[1][ix];
            aL[fm] = *(const bf16x8*)&sA[2][ix];
        }
#pragma unroll
        for (int fn = 0; fn < 4; ++fn) {
            int iy = swz(wn * 64 + fn * 16 + fr, fko);
            bf16x8 bY = *(const bf16x8*)&sB[0][iy];
            bf16x8 bH = *(const bf16x8*)&sB[1][iy];
            bf16x8 bL = *(const bf16x8*)&sB[2][iy];
#pragma unroll
            for (int fm = 0; fm < 4; ++fm) {
                axy[fm][fn] = __builtin_amdgcn_mfma_f32_16x16x32_bf16(aX[fm], bY, axy[fm][fn], 0, 0, 0);
                acb[fm][fn] = __builtin_amdgcn_mfma_f32_16x16x32_bf16(aH[fm], bH, acb[fm][fn], 0, 0, 0);
                acb[fm][fn] = __builtin_amdgcn_mfma_f32_16x16x32_bf16(aH[fm], bL, acb[fm][fn], 0, 0, 0);
                acb[fm][fn] = __builtin_amdgcn_mfma_f32_16x16x32_bf16(aL[fm], bH, acb[fm][fn], 0, 0, 0);
            }
        }
        __syncthreads();
    }

    float c0 = params[0], c1 = params[1], c2 = params[2], c3 = params[3];
    int fq = lane >> 4;
#pragma unroll
    for (int fm = 0; fm < 4; ++fm) {
#pragma unroll
        for (int fn = 0; fn < 4; ++fn) {
#pragma unroll
            for (int r = 0; r < 4; ++r) {
                int rl = wm * 64 + fm * 16 + fq * 4 + r;
                int cl = wn * 64 + fn * 16 + fr;
                float d = fmaxf(x2s[rl] + y2s[cl] - 2.0f * axy[fm][fn][r], 0.0f);
                float kv = __expf(-d * c0);
                out[(size_t)(bm * 128 + rl) * B_N + (bn * 128 + cl)] =
                    kv * (acb[fm][fn][r] - c1 * ysys[cl] + d * c2 - c3);
            }
        }
    }
}

// ---------------- Fallback main (round-1, in-kernel conversion) ----------------
static __device__ __forceinline__ void store_hi(unsigned short* tile, int r, int k0,
                                                float4 v0, float4 v1) {
    bf16x8 h;
    h[0] = (short)f2bf_rne(v0.x); h[1] = (short)f2bf_rne(v0.y);
    h[2] = (short)f2bf_rne(v0.z); h[3] = (short)f2bf_rne(v0.w);
    h[4] = (short)f2bf_rne(v1.x); h[5] = (short)f2bf_rne(v1.y);
    h[6] = (short)f2bf_rne(v1.z); h[7] = (short)f2bf_rne(v1.w);
    *(bf16x8*)&tile[swz(r, k0)] = h;
}
static __device__ __forceinline__ void store_hilo(unsigned short* th, unsigned short* tl,
                                                  int r, int k0, float4 v0, float4 v1) {
    float f[8] = {v0.x, v0.y, v0.z, v0.w, v1.x, v1.y, v1.z, v1.w};
    bf16x8 h, l;
#pragma unroll
    for (int j = 0; j < 8; ++j) {
        unsigned short hh = f2bf_rne(f[j]);
        h[j] = (short)hh;
        l[j] = (short)f2bf_rne(f[j] - bf2f(hh));
    }
    *(bf16x8*)&th[swz(r, k0)] = h;
    *(bf16x8*)&tl[swz(r, k0)] = l;
}

__global__ __launch_bounds__(256, 2) void k_main_fb(
    const float* __restrict__ X, const float* __restrict__ SX,
    const float* __restrict__ Y, const float* __restrict__ SY,
    const float* __restrict__ x2g, const float* __restrict__ y2g,
    const float* __restrict__ ysyg, const float* __restrict__ params,
    float* __restrict__ out) {
    __shared__ __align__(16) unsigned short tX[4096];
    __shared__ __align__(16) unsigned short tSXH[4096];
    __shared__ __align__(16) unsigned short tSXL[4096];
    __shared__ __align__(16) unsigned short tY[2048];
    __shared__ __align__(16) unsigned short tSYH[2048];
    __shared__ __align__(16) unsigned short tSYL[2048];
    __shared__ float x2s[128];
    __shared__ float y2s[64];
    __shared__ float ysys[64];

    int t = threadIdx.x;
    int bm = blockIdx.y, bn = blockIdx.x;
    if (t < 128) x2s[t] = x2g[bm * 128 + t];
    else if (t < 192) y2s[t - 128] = y2g[bn * 64 + (t - 128)];
    else ysys[t - 192] = ysyg[bn * 64 + (t - 192)];

    int lane = t & 63, w = t >> 6, wm = w >> 1, wn = w & 1;
    f32x4 axy[4][2], ass[4][2], axsy[4][2];
#pragma unroll
    for (int i = 0; i < 4; ++i)
#pragma unroll
        for (int j = 0; j < 2; ++j) {
            axy[i][j] = (f32x4)0.f; ass[i][j] = (f32x4)0.f; axsy[i][j] = (f32x4)0.f;
        }

    for (int kt = 0; kt < DIM / 32; ++kt) {
        int kb = kt * 32;
#pragma unroll
        for (int h = 0; h < 2; ++h) {
            int s = t + h * 256;
            int r = s >> 2, k0 = (s & 3) * 8;
            const float* gx = X + (size_t)(bm * 128 + r) * DIM + kb + k0;
            store_hi(tX, r, k0, *(const float4*)gx, *(const float4*)(gx + 4));
            const float* gs = SX + (size_t)(bm * 128 + r) * DIM + kb + k0;
            store_hilo(tSXH, tSXL, r, k0, *(const float4*)gs, *(const float4*)(gs + 4));
        }
        {
            int r = t >> 2, k0 = (t & 3) * 8;
            const float* gy = Y + (size_t)(bn * 64 + r) * DIM + kb + k0;
            store_hi(tY, r, k0, *(const float4*)gy, *(const float4*)(gy + 4));
            const float* gq = SY + (size_t)(bn * 64 + r) * DIM + kb + k0;
            store_hilo(tSYH, tSYL, r, k0, *(const float4*)gq, *(const float4*)(gq + 4));
        }
        __syncthreads();

        int fr = lane & 15, fk = (lane >> 4) * 8;
        bf16x8 aX[4], aSH[4], aSL[4];
#pragma unroll
        for (int fm = 0; fm < 4; ++fm) {
            int ix = swz(wm * 64 + fm * 16 + fr, fk);
            aX[fm] = *(const bf16x8*)&tX[ix];
            aSH[fm] = *(const bf16x8*)&tSXH[ix];
            aSL[fm] = *(const bf16x8*)&tSXL[ix];
        }
#pragma unroll
        for (int fn = 0; fn < 2; ++fn) {
            int iy = swz(wn * 32 + fn * 16 + fr, fk);
            bf16x8 bY = *(const bf16x8*)&tY[iy];
            bf16x8 bH = *(const bf16x8*)&tSYH[iy];
            bf16x8 bL = *(const bf16x8*)&tSYL[iy];
#pragma unroll
            for (int fm = 0; fm < 4; ++fm) {
                axy[fm][fn] = __builtin_amdgcn_mfma_f32_16x16x32_bf16(aX[fm], bY, axy[fm][fn], 0, 0, 0);
                ass[fm][fn] = __builtin_amdgcn_mfma_f32_16x16x32_bf16(aSH[fm], bH, ass[fm][fn], 0, 0, 0);
                ass[fm][fn] = __builtin_amdgcn_mfma_f32_16x16x32_bf16(aSH[fm], bL, ass[fm][fn], 0, 0, 0);
                ass[fm][fn] = __builtin_amdgcn_mfma_f32_16x16x32_bf16(aSL[fm], bH, ass[fm][fn], 0, 0, 0);
                axsy[fm][fn] = __builtin_amdgcn_mfma_f32_16x16x32_bf16(aX[fm], bH, axsy[fm][fn], 0, 0, 0);
            }
        }
        __syncthreads();
    }

    float c0 = params[0], c1 = params[1], c2 = params[2], c3 = params[3];
    int fr = lane & 15, fq = lane >> 4;
#pragma unroll
    for (int fm = 0; fm < 4; ++fm)
#pragma unroll
        for (int fn = 0; fn < 2; ++fn)
#pragma unroll
            for (int r = 0; r < 4; ++r) {
                int rl = wm * 64 + fm * 16 + fq * 4 + r;
                int cl = wn * 32 + fn * 16 + fr;
                float d = fmaxf(x2s[rl] + y2s[cl] - 2.0f * axy[fm][fn][r], 0.0f);
                float kv = __expf(-d * c0);
                out[(size_t)(bm * 128 + rl) * B_N + (bn * 64 + cl)] =
                    kv * ass[fm][fn][r] + (axsy[fm][fn][r] - ysys[cl]) * (kv * c1)
                    + d * kv * c2 - kv * c3;
            }
}

extern "C" void kernel_launch(void* const* d_in, const int* in_sizes, int n_in,
                              void* d_out, int out_size, void* d_ws, size_t ws_size,
                              hipStream_t stream) {
    const float* x  = (const float*)d_in[0];
    const float* sx = (const float*)d_in[1];
    const float* y  = (const float*)d_in[2];
    const float* sy = (const float*)d_in[3];
    float* out = (float*)d_out;
    char* ws = (char*)d_ws;
    unsigned int* hist = (unsigned int*)(ws + OFF_HIST);
    float* params = (float*)(ws + OFF_PARAMS);
    float* x2 = (float*)(ws + OFF_X2);
    float* y2 = (float*)(ws + OFF_Y2);
    float* ysy = (float*)(ws + OFF_YSY);
    unsigned short* tiles = (unsigned short*)(ws + OFF_TILES);

    hipMemsetAsync(hist, 0, HBINS * 4, stream);
    k_rowstats<<<B_N, 128, 0, stream>>>(x, y, sy, x2, y2, ysy);
    k_hist<<<dim3(16, 16), dim3(256), 0, stream>>>(x, y, x2, y2, hist);
    k_median<<<1, 256, 0, stream>>>(hist, params);

    if (ws_size >= WS_NEED) {
        k_preB<<<dim3(32, 16), dim3(256), 0, stream>>>(y, sy, tiles);
        k_preA<<<dim3(32, 16), dim3(256), 0, stream>>>(x, sx, params, tiles);
        k_main<<<dim3(32, 32), dim3(256), 0, stream>>>(tiles, x2, y2, ysy, params, out);
    } else {
        k_main_fb<<<dim3(64, 32), dim3(256), 0, stream>>>(x, sx, y, sy, x2, y2, ysy, params, out);
    }
}

// Round 4
// 111.798 us; speedup vs baseline: 1.9201x; 1.2231x over previous
//
#include <hip/hip_runtime.h>
#include <hip/hip_bf16.h>

typedef __attribute__((ext_vector_type(8))) short bf16x8;
typedef __attribute__((ext_vector_type(4))) float f32x4;

#define B_N 4096
#define DIM 512
#define HBINS 8192

// workspace byte offsets
#define OFF_HIST   0                 // 8192*4 = 32768
#define OFF_PARAMS 32768             // 256
#define OFF_X2     33024
#define OFF_Y2     49408
#define OFF_YSY    65792
#define OFF_TILES  98304             // 4KB aligned
#define MAT_ELEMS  2097152           // 4096*512 bf16 elems per matrix (4 MB)
#define WS_NEED    (OFF_TILES + (size_t)4 * MAT_ELEMS * 2)

static __device__ __forceinline__ unsigned short f2bf_rne(float f) {
    unsigned int u = __float_as_uint(f);
    u += 0x7FFFu + ((u >> 16) & 1u);
    return (unsigned short)(u >> 16);
}
static __device__ __forceinline__ float bf2f(unsigned short h) {
    return __uint_as_float(((unsigned int)h) << 16);
}

// swizzled tile index (elements); row stride 32 bf16 = 64B; 16B slot ^= (row>>1)&3
static __device__ __forceinline__ int swz(int r, int k) {
    return r * 32 + ((((k >> 3) ^ ((r >> 1) & 3))) << 3) + (k & 7);
}

// ---------------- K1: row stats: x2[i], y2[j], ysy[j] (wave per row) ----------------
__global__ void k_rowstats(const float* __restrict__ X, const float* __restrict__ Y,
                           const float* __restrict__ SY,
                           float* __restrict__ x2, float* __restrict__ y2,
                           float* __restrict__ ysy) {
    int t = threadIdx.x;                     // 256 = 4 waves
    int r = blockIdx.x * 4 + (t >> 6);
    int lane = t & 63;
    const float4* px = (const float4*)(X + (size_t)r * DIM) + lane * 2;
    const float4* py = (const float4*)(Y + (size_t)r * DIM) + lane * 2;
    const float4* ps = (const float4*)(SY + (size_t)r * DIM) + lane * 2;
    float4 a0 = px[0], a1 = px[1];
    float4 b0 = py[0], b1 = py[1];
    float4 c0 = ps[0], c1 = ps[1];
    float s1 = a0.x*a0.x + a0.y*a0.y + a0.z*a0.z + a0.w*a0.w
             + a1.x*a1.x + a1.y*a1.y + a1.z*a1.z + a1.w*a1.w;
    float s2 = b0.x*b0.x + b0.y*b0.y + b0.z*b0.z + b0.w*b0.w
             + b1.x*b1.x + b1.y*b1.y + b1.z*b1.z + b1.w*b1.w;
    float s3 = b0.x*c0.x + b0.y*c0.y + b0.z*c0.z + b0.w*c0.w
             + b1.x*c1.x + b1.y*c1.y + b1.z*c1.z + b1.w*c1.w;
#pragma unroll
    for (int o = 32; o > 0; o >>= 1) {
        s1 += __shfl_down(s1, o);
        s2 += __shfl_down(s2, o);
        s3 += __shfl_down(s3, o);
    }
    if (lane == 0) { x2[r] = s1; y2[r] = s2; ysy[r] = s3; }
}

// ---------------- K2: sample dist^2 histogram, LDS-local ----------------
__global__ void k_hist(const float* __restrict__ X, const float* __restrict__ Y,
                       const float* __restrict__ x2, const float* __restrict__ y2,
                       unsigned int* __restrict__ hist) {
    __shared__ float xs[32][68];
    __shared__ float ys[32][68];
    __shared__ unsigned int hloc[HBINS];
    int t = threadIdx.x;  // 256
    for (int i = t; i < HBINS; i += 256) hloc[i] = 0;
    int i0 = blockIdx.y * 32, j0 = blockIdx.x * 32;
    float a00 = 0.f, a01 = 0.f, a10 = 0.f, a11 = 0.f;
    int ti = (t >> 4) * 2, tj = (t & 15) * 2;
    for (int c = 0; c < 8; ++c) {
        __syncthreads();
        int rr = t >> 3, cc = (t & 7) * 8;
        const float* gx = X + (size_t)(i0 + rr) * DIM + c * 64 + cc;
        *(float4*)&xs[rr][cc] = *(const float4*)gx;
        *(float4*)&xs[rr][cc + 4] = *(const float4*)(gx + 4);
        const float* gy = Y + (size_t)(j0 + rr) * DIM + c * 64 + cc;
        *(float4*)&ys[rr][cc] = *(const float4*)gy;
        *(float4*)&ys[rr][cc + 4] = *(const float4*)(gy + 4);
        __syncthreads();
        for (int kk = 0; kk < 64; ++kk) {
            float a0 = xs[ti][kk], a1 = xs[ti + 1][kk];
            float b0 = ys[tj][kk], b1 = ys[tj + 1][kk];
            a00 += a0 * b0; a01 += a0 * b1; a10 += a1 * b0; a11 += a1 * b1;
        }
    }
    float s[2][2] = {{a00, a01}, {a10, a11}};
#pragma unroll
    for (int ii = 0; ii < 2; ++ii)
#pragma unroll
        for (int jj = 0; jj < 2; ++jj) {
            float d = fmaxf(x2[i0 + ti + ii] + y2[j0 + tj + jj] - 2.f * s[ii][jj], 0.f);
            int bin = (int)(d * 4.0f);
            if (bin > HBINS - 1) bin = HBINS - 1;
            atomicAdd(&hloc[bin], 1u);
        }
    __syncthreads();
    for (int i = t; i < HBINS; i += 256) {
        unsigned int v = hloc[i];
        if (v) atomicAdd(&hist[i], v);
    }
}

// ---------------- K3: median -> bandwidth params ----------------
__global__ void k_median(const unsigned int* __restrict__ hist, float* __restrict__ params) {
    __shared__ unsigned int part[256];
    int t = threadIdx.x;
    unsigned int s = 0;
    for (int i = 0; i < 32; ++i) s += hist[t * 32 + i];
    part[t] = s;
    __syncthreads();
    if (t == 0) {
        const unsigned int k1 = 131072u, k2 = 131073u;
        float v1 = 0.f, v2 = 0.f;
        int got = 0;
        unsigned int c = 0;
        for (int ch = 0; ch < 256 && got < 2; ++ch) {
            unsigned int nc = c + part[ch];
            if (got < 1 && k1 <= nc) {
                unsigned int cc = c;
                for (int b = 0; b < 32; ++b) {
                    cc += hist[ch * 32 + b];
                    if (cc >= k1) { v1 = ((float)(ch * 32 + b) + 0.5f) * 0.25f; break; }
                }
                got = 1;
            }
            if (got >= 1 && k2 <= nc) {
                unsigned int cc = c;
                for (int b = 0; b < 32; ++b) {
                    cc += hist[ch * 32 + b];
                    if (cc >= k2) { v2 = ((float)(ch * 32 + b) + 0.5f) * 0.25f; break; }
                }
                got = 2;
            }
            c = nc;
        }
        float med = 0.5f * (v1 + v2);
        float bw = sqrtf(med * 0.5f);
        bw = fminf(fmaxf(bw, 0.1f), 10.0f);
        float h2 = bw * bw;
        params[0] = 1.0f / (2.0f * h2);
        params[1] = 1.0f / h2;
        params[2] = 1.0f / (h2 * h2);
        params[3] = (float)DIM / h2;
    }
}

// ---------------- K4: precompute bf16 tile images (both sides) ----------------
// side 0 (z=0): mat0 = bf16(X), mat1 = bf16(SX + c1*X)
// side 1 (z=1): mat2 = bf16(Y), mat3 = bf16(SY)
// Layout: mat*MAT_ELEMS + (tile*16 + kt)*4096 + swz(r,k)
__global__ void k_pre(const float* __restrict__ X, const float* __restrict__ SX,
                      const float* __restrict__ Y, const float* __restrict__ SY,
                      const float* __restrict__ params, unsigned short* __restrict__ tiles) {
    int side = blockIdx.z;
    const float* P = side ? Y : X;
    const float* Q = side ? SY : SX;
    float c1 = side ? 0.0f : params[1];
    int tile = blockIdx.x, kt = blockIdx.y, t = threadIdx.x;
    int r = t >> 1, k0 = (t & 1) * 16;
    const float* gp = P + (size_t)(tile * 128 + r) * DIM + kt * 32 + k0;
    const float* gq = Q + (size_t)(tile * 128 + r) * DIM + kt * 32 + k0;
    unsigned short* d0 = tiles + (size_t)side * 2 * MAT_ELEMS + (size_t)(tile * 16 + kt) * 4096;
    unsigned short* d1 = d0 + MAT_ELEMS;
#pragma unroll
    for (int half = 0; half < 2; ++half) {
        float4 p0 = *(const float4*)(gp + half * 8);
        float4 p1 = *(const float4*)(gp + half * 8 + 4);
        float4 q0 = *(const float4*)(gq + half * 8);
        float4 q1 = *(const float4*)(gq + half * 8 + 4);
        float pv[8] = {p0.x, p0.y, p0.z, p0.w, p1.x, p1.y, p1.z, p1.w};
        float qv[8] = {q0.x, q0.y, q0.z, q0.w, q1.x, q1.y, q1.z, q1.w};
        bf16x8 h0, h1;
#pragma unroll
        for (int j = 0; j < 8; ++j) {
            h0[j] = (short)f2bf_rne(pv[j]);
            h1[j] = (short)f2bf_rne(qv[j] + c1 * pv[j]);
        }
        int ix = swz(r, k0 + half * 8);
        *(bf16x8*)&d0[ix] = h0;
        *(bf16x8*)&d1[ix] = h1;
    }
}

// ---------------- K5: main fused 2-GEMM + epilogue, dbuf pipeline ----------------
#define GLD(g, l) __builtin_amdgcn_global_load_lds(                                   \
    (const __attribute__((address_space(1))) void*)(g),                               \
    (__attribute__((address_space(3))) void*)(l), 16, 0, 0)

__global__ __launch_bounds__(256, 2) void k_main(
    const unsigned short* __restrict__ tiles,
    const float* __restrict__ x2g, const float* __restrict__ y2g,
    const float* __restrict__ ysyg, const float* __restrict__ params,
    float* __restrict__ out) {
    __shared__ __align__(16) unsigned short sA[2][2][4096];  // [buf][{X,C}] 128x32 swizzled
    __shared__ __align__(16) unsigned short sB[2][2][4096];  // [buf][{Y,SY}]
    __shared__ float x2s[128], y2s[128], ysys[128];

    int t = threadIdx.x;
    int bm = blockIdx.y, bn = blockIdx.x;
    if (t < 128) x2s[t] = x2g[bm * 128 + t];
    else { y2s[t - 128] = y2g[bn * 128 + (t - 128)]; ysys[t - 128] = ysyg[bn * 128 + (t - 128)]; }
    __syncthreads();

    int lane = t & 63, w = t >> 6;
    int wm = w >> 1, wn = w & 1;       // wave tile 64x64 at (wm*64, wn*64)
    int fr = lane & 15, fko = (lane >> 4) * 8;

    f32x4 axy[4][4], acb[4][4];
#pragma unroll
    for (int i = 0; i < 4; ++i)
#pragma unroll
        for (int j = 0; j < 4; ++j) { axy[i][j] = (f32x4)0.f; acb[i][j] = (f32x4)0.f; }

    const unsigned short* ga = tiles + (size_t)(bm * 16) * 4096 + t * 8;
    const unsigned short* gb = tiles + (size_t)2 * MAT_ELEMS + (size_t)(bn * 16) * 4096 + t * 8;

#define STAGE(buf, kt_) do {                                                     \
        const unsigned short* pa_ = ga + (size_t)(kt_) * 4096;                   \
        const unsigned short* pb_ = gb + (size_t)(kt_) * 4096;                   \
        GLD(pa_,                      &sA[buf][0][t * 8]);                       \
        GLD(pa_ + 2048,               &sA[buf][0][2048 + t * 8]);                \
        GLD(pa_ + MAT_ELEMS,          &sA[buf][1][t * 8]);                       \
        GLD(pa_ + MAT_ELEMS + 2048,   &sA[buf][1][2048 + t * 8]);                \
        GLD(pb_,                      &sB[buf][0][t * 8]);                       \
        GLD(pb_ + 2048,               &sB[buf][0][2048 + t * 8]);                \
        GLD(pb_ + MAT_ELEMS,          &sB[buf][1][t * 8]);                       \
        GLD(pb_ + MAT_ELEMS + 2048,   &sB[buf][1][2048 + t * 8]);                \
    } while (0)

    int ixA[4], ixB[4];
#pragma unroll
    for (int fm = 0; fm < 4; ++fm) ixA[fm] = swz(wm * 64 + fm * 16 + fr, fko);
#pragma unroll
    for (int fn = 0; fn < 4; ++fn) ixB[fn] = swz(wn * 64 + fn * 16 + fr, fko);

    STAGE(0, 0);

    for (int kt = 0; kt < 16; ++kt) {
        int cb = kt & 1;
        if (kt < 15) {
            STAGE(cb ^ 1, kt + 1);
            asm volatile("s_waitcnt vmcnt(8)" ::: "memory");   // cur buf's 8 loads done; next 8 in flight
        } else {
            asm volatile("s_waitcnt vmcnt(0)" ::: "memory");
        }
        __builtin_amdgcn_sched_barrier(0);
        __builtin_amdgcn_s_barrier();                          // cur buf ready for all waves

        bf16x8 aX[4], aC[4], bY[4], bS[4];
#pragma unroll
        for (int fm = 0; fm < 4; ++fm) {
            aX[fm] = *(const bf16x8*)&sA[cb][0][ixA[fm]];
            aC[fm] = *(const bf16x8*)&sA[cb][1][ixA[fm]];
        }
#pragma unroll
        for (int fn = 0; fn < 4; ++fn) {
            bY[fn] = *(const bf16x8*)&sB[cb][0][ixB[fn]];
            bS[fn] = *(const bf16x8*)&sB[cb][1][ixB[fn]];
        }
        asm volatile("s_waitcnt lgkmcnt(0)" ::: "memory");     // my reads landed in regs
        __builtin_amdgcn_sched_barrier(0);
        __builtin_amdgcn_s_barrier();                          // all waves done reading cur buf

#pragma unroll
        for (int fn = 0; fn < 4; ++fn)
#pragma unroll
            for (int fm = 0; fm < 4; ++fm) {
                axy[fm][fn] = __builtin_amdgcn_mfma_f32_16x16x32_bf16(aX[fm], bY[fn], axy[fm][fn], 0, 0, 0);
                acb[fm][fn] = __builtin_amdgcn_mfma_f32_16x16x32_bf16(aC[fm], bS[fn], acb[fm][fn], 0, 0, 0);
            }
    }
#undef STAGE

    float c0 = params[0], c1 = params[1], c2 = params[2], c3 = params[3];
    int fq = lane >> 4;
#pragma unroll
    for (int fm = 0; fm < 4; ++fm) {
#pragma unroll
        for (int fn = 0; fn < 4; ++fn) {
#pragma unroll
            for (int r = 0; r < 4; ++r) {
                int rl = wm * 64 + fm * 16 + fq * 4 + r;
                int cl = wn * 64 + fn * 16 + fr;
                float d = fmaxf(x2s[rl] + y2s[cl] - 2.0f * axy[fm][fn][r], 0.0f);
                float kv = __expf(-d * c0);
                out[(size_t)(bm * 128 + rl) * B_N + (bn * 128 + cl)] =
                    kv * (acb[fm][fn][r] - c1 * ysys[cl] + d * c2 - c3);
            }
        }
    }
}

// ---------------- Fallback main (in-kernel conversion, known-good) ----------------
static __device__ __forceinline__ void store_hi(unsigned short* tile, int r, int k0,
                                                float4 v0, float4 v1) {
    bf16x8 h;
    h[0] = (short)f2bf_rne(v0.x); h[1] = (short)f2bf_rne(v0.y);
    h[2] = (short)f2bf_rne(v0.z); h[3] = (short)f2bf_rne(v0.w);
    h[4] = (short)f2bf_rne(v1.x); h[5] = (short)f2bf_rne(v1.y);
    h[6] = (short)f2bf_rne(v1.z); h[7] = (short)f2bf_rne(v1.w);
    *(bf16x8*)&tile[swz(r, k0)] = h;
}
static __device__ __forceinline__ void store_hilo(unsigned short* th, unsigned short* tl,
                                                  int r, int k0, float4 v0, float4 v1) {
    float f[8] = {v0.x, v0.y, v0.z, v0.w, v1.x, v1.y, v1.z, v1.w};
    bf16x8 h, l;
#pragma unroll
    for (int j = 0; j < 8; ++j) {
        unsigned short hh = f2bf_rne(f[j]);
        h[j] = (short)hh;
        l[j] = (short)f2bf_rne(f[j] - bf2f(hh));
    }
    *(bf16x8*)&th[swz(r, k0)] = h;
    *(bf16x8*)&tl[swz(r, k0)] = l;
}

__global__ __launch_bounds__(256, 2) void k_main_fb(
    const float* __restrict__ X, const float* __restrict__ SX,
    const float* __restrict__ Y, const float* __restrict__ SY,
    const float* __restrict__ x2g, const float* __restrict__ y2g,
    const float* __restrict__ ysyg, const float* __restrict__ params,
    float* __restrict__ out) {
    __shared__ __align__(16) unsigned short tX[4096];
    __shared__ __align__(16) unsigned short tSXH[4096];
    __shared__ __align__(16) unsigned short tSXL[4096];
    __shared__ __align__(16) unsigned short tY[2048];
    __shared__ __align__(16) unsigned short tSYH[2048];
    __shared__ __align__(16) unsigned short tSYL[2048];
    __shared__ float x2s[128];
    __shared__ float y2s[64];
    __shared__ float ysys[64];

    int t = threadIdx.x;
    int bm = blockIdx.y, bn = blockIdx.x;
    if (t < 128) x2s[t] = x2g[bm * 128 + t];
    else if (t < 192) y2s[t - 128] = y2g[bn * 64 + (t - 128)];
    else ysys[t - 192] = ysyg[bn * 64 + (t - 192)];

    int lane = t & 63, w = t >> 6, wm = w >> 1, wn = w & 1;
    f32x4 axy[4][2], ass[4][2], axsy[4][2];
#pragma unroll
    for (int i = 0; i < 4; ++i)
#pragma unroll
        for (int j = 0; j < 2; ++j) {
            axy[i][j] = (f32x4)0.f; ass[i][j] = (f32x4)0.f; axsy[i][j] = (f32x4)0.f;
        }

    for (int kt = 0; kt < DIM / 32; ++kt) {
        int kb = kt * 32;
#pragma unroll
        for (int h = 0; h < 2; ++h) {
            int s = t + h * 256;
            int r = s >> 2, k0 = (s & 3) * 8;
            const float* gx = X + (size_t)(bm * 128 + r) * DIM + kb + k0;
            store_hi(tX, r, k0, *(const float4*)gx, *(const float4*)(gx + 4));
            const float* gs = SX + (size_t)(bm * 128 + r) * DIM + kb + k0;
            store_hilo(tSXH, tSXL, r, k0, *(const float4*)gs, *(const float4*)(gs + 4));
        }
        {
            int r = t >> 2, k0 = (t & 3) * 8;
            const float* gy = Y + (size_t)(bn * 64 + r) * DIM + kb + k0;
            store_hi(tY, r, k0, *(const float4*)gy, *(const float4*)(gy + 4));
            const float* gq = SY + (size_t)(bn * 64 + r) * DIM + kb + k0;
            store_hilo(tSYH, tSYL, r, k0, *(const float4*)gq, *(const float4*)(gq + 4));
        }
        __syncthreads();

        int fr = lane & 15, fk = (lane >> 4) * 8;
        bf16x8 aX[4], aSH[4], aSL[4];
#pragma unroll
        for (int fm = 0; fm < 4; ++fm) {
            int ix = swz(wm * 64 + fm * 16 + fr, fk);
            aX[fm] = *(const bf16x8*)&tX[ix];
            aSH[fm] = *(const bf16x8*)&tSXH[ix];
            aSL[fm] = *(const bf16x8*)&tSXL[ix];
        }
#pragma unroll
        for (int fn = 0; fn < 2; ++fn) {
            int iy = swz(wn * 32 + fn * 16 + fr, fk);
            bf16x8 bY = *(const bf16x8*)&tY[iy];
            bf16x8 bH = *(const bf16x8*)&tSYH[iy];
            bf16x8 bL = *(const bf16x8*)&tSYL[iy];
#pragma unroll
            for (int fm = 0; fm < 4; ++fm) {
                axy[fm][fn] = __builtin_amdgcn_mfma_f32_16x16x32_bf16(aX[fm], bY, axy[fm][fn], 0, 0, 0);
                ass[fm][fn] = __builtin_amdgcn_mfma_f32_16x16x32_bf16(aSH[fm], bH, ass[fm][fn], 0, 0, 0);
                ass[fm][fn] = __builtin_amdgcn_mfma_f32_16x16x32_bf16(aSH[fm], bL, ass[fm][fn], 0, 0, 0);
                ass[fm][fn] = __builtin_amdgcn_mfma_f32_16x16x32_bf16(aSL[fm], bH, ass[fm][fn], 0, 0, 0);
                axsy[fm][fn] = __builtin_amdgcn_mfma_f32_16x16x32_bf16(aX[fm], bH, axsy[fm][fn], 0, 0, 0);
            }
        }
        __syncthreads();
    }

    float c0 = params[0], c1 = params[1], c2 = params[2], c3 = params[3];
    int fr = lane & 15, fq = lane >> 4;
#pragma unroll
    for (int fm = 0; fm < 4; ++fm)
#pragma unroll
        for (int fn = 0; fn < 2; ++fn)
#pragma unroll
            for (int r = 0; r < 4; ++r) {
                int rl = wm * 64 + fm * 16 + fq * 4 + r;
                int cl = wn * 32 + fn * 16 + fr;
                float d = fmaxf(x2s[rl] + y2s[cl] - 2.0f * axy[fm][fn][r], 0.0f);
                float kv = __expf(-d * c0);
                out[(size_t)(bm * 128 + rl) * B_N + (bn * 64 + cl)] =
                    kv * ass[fm][fn][r] + (axsy[fm][fn][r] - ysys[cl]) * (kv * c1)
                    + d * kv * c2 - kv * c3;
            }
}

extern "C" void kernel_launch(void* const* d_in, const int* in_sizes, int n_in,
                              void* d_out, int out_size, void* d_ws, size_t ws_size,
                              hipStream_t stream) {
    const float* x  = (const float*)d_in[0];
    const float* sx = (const float*)d_in[1];
    const float* y  = (const float*)d_in[2];
    const float* sy = (const float*)d_in[3];
    float* out = (float*)d_out;
    char* ws = (char*)d_ws;
    unsigned int* hist = (unsigned int*)(ws + OFF_HIST);
    float* params = (float*)(ws + OFF_PARAMS);
    float* x2 = (float*)(ws + OFF_X2);
    float* y2 = (float*)(ws + OFF_Y2);
    float* ysy = (float*)(ws + OFF_YSY);
    unsigned short* tiles = (unsigned short*)(ws + OFF_TILES);

    hipMemsetAsync(hist, 0, HBINS * 4, stream);
    k_rowstats<<<B_N / 4, 256, 0, stream>>>(x, y, sy, x2, y2, ysy);
    k_hist<<<dim3(16, 16), dim3(256), 0, stream>>>(x, y, x2, y2, hist);
    k_median<<<1, 256, 0, stream>>>(hist, params);

    if (ws_size >= WS_NEED) {
        k_pre<<<dim3(32, 16, 2), dim3(256), 0, stream>>>(x, sx, y, sy, params, tiles);
        k_main<<<dim3(32, 32), dim3(256), 0, stream>>>(tiles, x2, y2, ysy, params, out);
    } else {
        k_main_fb<<<dim3(64, 32), dim3(256), 0, stream>>>(x, sx, y, sy, x2, y2, ysy, params, out);
    }
}